// Round 1
// baseline (164.269 us; speedup 1.0000x reference)
//
#include <hip/hip_runtime.h>
#include <math.h>

#define NB 32
#define NA 5
#define NC 20
#define NH 76
#define NW 76
#define MAXT 50
#define NHW (NH * NW)               // 5776
#define CH (5 + NC)                 // 25
#define CELLS_PER_IMG (NA * NHW)    // 28880
#define SIL 0.6f

__global__ void zero_out_kernel(float* out) { out[0] = 0.0f; }

__device__ __forceinline__ float sigmoidf_(float v) {
    return 1.0f / (1.0f + __expf(-v));
}

__global__ __launch_bounds__(256) void yolo_loss_kernel(
    const float* __restrict__ out, const float* __restrict__ target,
    const float* __restrict__ anchors, float* __restrict__ loss)
{
    __shared__ float s_aw[NA], s_ah[NA];
    __shared__ float s_gx[MAXT], s_gy[MAXT], s_gw[MAXT], s_gh[MAXT];
    __shared__ int   s_cell[MAXT];
    __shared__ int   s_cnt;
    __shared__ float s_part[4];

    const int tid = threadIdx.x;
    const int b   = blockIdx.y;

    if (tid < NA) { s_aw[tid] = anchors[2 * tid]; s_ah[tid] = anchors[2 * tid + 1]; }
    if (tid == 0) s_cnt = 0;
    __syncthreads();

    float lsum = 0.0f;

    // ---- phase 1: per-target processing (threads 0..MAXT-1) ----
    if (tid < MAXT) {
        const float* tp = target + (size_t)b * MAXT * 5 + tid * 5;
        float tc = tp[0], xn = tp[1], yn = tp[2], wn = tp[3], hn = tp[4];
        if (xn != 0.0f) {  // valid
            float gx = xn * NW, gy = yn * NH, gw = wn * NW, gh = hn * NH;

            // best anchor by centered-box IoU (first index on ties)
            int bn = 0; float best = -1.0f;
            #pragma unroll
            for (int a = 0; a < NA; ++a) {
                float mw = fminf(gw, s_aw[a]);
                float mh = fminf(gh, s_ah[a]);
                float car = mw * mh;
                float iou = car / (gw * gh + s_aw[a] * s_ah[a] - car);
                if (iou > best) { best = iou; bn = a; }
            }
            int gi = (int)gx; gi = gi < 0 ? 0 : (gi > NW - 1 ? NW - 1 : gi);
            int gj = (int)gy; gj = gj < 0 ? 0 : (gj > NH - 1 ? NH - 1 : gj);

            int pos = atomicAdd(&s_cnt, 1);
            s_gx[pos] = gx; s_gy[pos] = gy; s_gw[pos] = gw; s_gh[pos] = gh;
            s_cell[pos] = bn * NHW + gj * NW + gi;   // per-image cell key

            // coord + class loss: once per target, done only by block x==0
            if (blockIdx.x == 0) {
                float tx = gx - gi, ty = gy - gj;
                float tw = __logf(gw / s_aw[bn]);
                float th = __logf(gh / s_ah[bn]);
                const float* cp = out + ((size_t)(b * NA + bn) * CH) * NHW + gj * NW + gi;
                float xr = sigmoidf_(cp[0]);
                float yr = sigmoidf_(cp[(size_t)1 * NHW]);
                float wr = cp[(size_t)2 * NHW];
                float hr = cp[(size_t)3 * NHW];
                lsum += 0.5f * ((xr - tx) * (xr - tx) + (yr - ty) * (yr - ty) +
                                (wr - tw) * (wr - tw) + (hr - th) * (hr - th));
                // class cross-entropy via log-sum-exp
                int c = (int)tc;
                float lg[NC];
                float m = -1e30f;
                #pragma unroll
                for (int k = 0; k < NC; ++k) {
                    lg[k] = cp[(size_t)(5 + k) * NHW];
                    m = fmaxf(m, lg[k]);
                }
                float s = 0.0f;
                #pragma unroll
                for (int k = 0; k < NC; ++k) s += __expf(lg[k] - m);
                lsum += (m + __logf(s)) - lg[c];
            }
        }
    }
    __syncthreads();

    // ---- phase 2: per-cell conf loss ----
    int cell = blockIdx.x * 256 + tid;
    if (cell < CELLS_PER_IMG) {
        int a = cell / NHW;
        int r = cell - a * NHW;
        int j = r / NW;
        int i = r - j * NW;
        const float* cp = out + ((size_t)(b * NA + a) * CH) * NHW + r;
        float px = sigmoidf_(cp[0]) + (float)i;
        float py = sigmoidf_(cp[(size_t)1 * NHW]) + (float)j;
        float pw = __expf(cp[(size_t)2 * NHW]) * s_aw[a];
        float ph = __expf(cp[(size_t)3 * NHW]) * s_ah[a];
        float conf = sigmoidf_(cp[(size_t)4 * NHW]);

        float parea = pw * ph;
        float maxiou = 0.0f, tconf = 0.0f;
        bool obj = false;
        int cnt = s_cnt;
        for (int u = 0; u < cnt; ++u) {
            float bx = s_gx[u], by = s_gy[u], bw = s_gw[u], bh = s_gh[u];
            float uw = fmaxf(px + pw * 0.5f, bx + bw * 0.5f) - fminf(px - pw * 0.5f, bx - bw * 0.5f);
            float uh = fmaxf(py + ph * 0.5f, by + bh * 0.5f) - fminf(py - ph * 0.5f, by - bh * 0.5f);
            float cw = pw + bw - uw, chh = ph + bh - uh;
            float iou = 0.0f;
            if (cw > 0.0f && chh > 0.0f) {
                float car = cw * chh;
                iou = car / (parea + bw * bh - car);
            }
            maxiou = fmaxf(maxiou, iou);
            if (s_cell[u] == cell) { obj = true; tconf = iou; }  // IoU is symmetric => tconf
        }
        float d = conf - (obj ? tconf : 0.0f);
        float scale = obj ? 5.0f : (maxiou > SIL ? 0.0f : 1.0f);
        lsum += 0.5f * scale * d * d;
    }

    // ---- block reduction + global atomic ----
    for (int o = 32; o > 0; o >>= 1) lsum += __shfl_down(lsum, o, 64);
    if ((tid & 63) == 0) s_part[tid >> 6] = lsum;
    __syncthreads();
    if (tid == 0) {
        float t = s_part[0] + s_part[1] + s_part[2] + s_part[3];
        atomicAdd(loss, t * (1.0f / NB));
    }
}

extern "C" void kernel_launch(void* const* d_in, const int* in_sizes, int n_in,
                              void* d_out, int out_size, void* d_ws, size_t ws_size,
                              hipStream_t stream) {
    const float* out_p    = (const float*)d_in[0];
    const float* target_p = (const float*)d_in[1];
    const float* anchor_p = (const float*)d_in[2];
    float* loss_p = (float*)d_out;

    zero_out_kernel<<<dim3(1), dim3(1), 0, stream>>>(loss_p);
    dim3 grid((CELLS_PER_IMG + 255) / 256, NB);
    yolo_loss_kernel<<<grid, dim3(256), 0, stream>>>(out_p, target_p, anchor_p, loss_p);
}

// Round 2
// 134.060 us; speedup vs baseline: 1.2253x; 1.2253x over previous
//
#include <hip/hip_runtime.h>
#include <math.h>

#define NB 32
#define NA 5
#define NC 20
#define NH 76
#define NW 76
#define MAXT 50
#define NHW (NH * NW)               // 5776
#define CH (5 + NC)                 // 25
#define CELLS_PER_IMG (NA * NHW)    // 28880
#define SIL 0.6f

#define CPT 4                                            // cells per thread
#define P2_BLOCKS ((CELLS_PER_IMG + 256 * CPT - 1) / (256 * CPT))   // 29
#define TOTAL_BLOCKS (P2_BLOCKS * NB)                    // 928

__device__ __forceinline__ float sigmoidf_(float v) {
    return 1.0f / (1.0f + __expf(-v));
}

__global__ __launch_bounds__(256) void yolo_loss_kernel(
    const float* __restrict__ out, const float* __restrict__ target,
    const float* __restrict__ anchors, float* __restrict__ partials)
{
    __shared__ float s_aw[NA], s_ah[NA];
    __shared__ float s_gx[MAXT], s_gy[MAXT], s_gw[MAXT], s_gh[MAXT];
    __shared__ int   s_cell[MAXT];
    __shared__ int   s_cnt;
    __shared__ float s_part[4];

    const int tid = threadIdx.x;
    const int b   = blockIdx.y;

    if (tid < NA) { s_aw[tid] = anchors[2 * tid]; s_ah[tid] = anchors[2 * tid + 1]; }
    if (tid == 0) s_cnt = 0;
    __syncthreads();

    float lsum = 0.0f;

    // ---- phase 1: per-target processing (threads 0..MAXT-1) ----
    if (tid < MAXT) {
        const float* tp = target + (size_t)b * MAXT * 5 + tid * 5;
        float tc = tp[0], xn = tp[1], yn = tp[2], wn = tp[3], hn = tp[4];
        if (xn != 0.0f) {  // valid
            float gx = xn * NW, gy = yn * NH, gw = wn * NW, gh = hn * NH;

            // best anchor by centered-box IoU (first index on ties)
            int bn = 0; float best = -1.0f;
            #pragma unroll
            for (int a = 0; a < NA; ++a) {
                float mw = fminf(gw, s_aw[a]);
                float mh = fminf(gh, s_ah[a]);
                float car = mw * mh;
                float iou = car / (gw * gh + s_aw[a] * s_ah[a] - car);
                if (iou > best) { best = iou; bn = a; }
            }
            int gi = (int)gx; gi = gi < 0 ? 0 : (gi > NW - 1 ? NW - 1 : gi);
            int gj = (int)gy; gj = gj < 0 ? 0 : (gj > NH - 1 ? NH - 1 : gj);

            int pos = atomicAdd(&s_cnt, 1);
            s_gx[pos] = gx; s_gy[pos] = gy; s_gw[pos] = gw; s_gh[pos] = gh;
            s_cell[pos] = bn * NHW + gj * NW + gi;   // per-image cell key

            // coord + class loss: once per target, done only by block x==0
            if (blockIdx.x == 0) {
                float tx = gx - gi, ty = gy - gj;
                float tw = __logf(gw / s_aw[bn]);
                float th = __logf(gh / s_ah[bn]);
                const float* cp = out + ((size_t)(b * NA + bn) * CH) * NHW + gj * NW + gi;
                float xr = sigmoidf_(cp[0]);
                float yr = sigmoidf_(cp[(size_t)1 * NHW]);
                float wr = cp[(size_t)2 * NHW];
                float hr = cp[(size_t)3 * NHW];
                lsum += 0.5f * ((xr - tx) * (xr - tx) + (yr - ty) * (yr - ty) +
                                (wr - tw) * (wr - tw) + (hr - th) * (hr - th));
                // class cross-entropy via log-sum-exp
                int c = (int)tc;
                float lg[NC];
                float m = -1e30f;
                #pragma unroll
                for (int k = 0; k < NC; ++k) {
                    lg[k] = cp[(size_t)(5 + k) * NHW];
                    m = fmaxf(m, lg[k]);
                }
                float s = 0.0f;
                #pragma unroll
                for (int k = 0; k < NC; ++k) s += __expf(lg[k] - m);
                lsum += (m + __logf(s)) - lg[c];
            }
        }
    }
    __syncthreads();

    // ---- phase 2: per-cell conf loss, CPT cells per thread ----
    const int cnt = s_cnt;
    #pragma unroll
    for (int c = 0; c < CPT; ++c) {
        int cell = (blockIdx.x * CPT + c) * 256 + tid;
        if (cell < CELLS_PER_IMG) {
            int a = cell / NHW;
            int r = cell - a * NHW;
            int j = r / NW;
            int i = r - j * NW;
            const float* cp = out + ((size_t)(b * NA + a) * CH) * NHW + r;
            float px = sigmoidf_(cp[0]) + (float)i;
            float py = sigmoidf_(cp[(size_t)1 * NHW]) + (float)j;
            float pw = __expf(cp[(size_t)2 * NHW]) * s_aw[a];
            float ph = __expf(cp[(size_t)3 * NHW]) * s_ah[a];
            float conf = sigmoidf_(cp[(size_t)4 * NHW]);

            float parea = pw * ph;
            float maxiou = 0.0f, tconf = 0.0f;
            bool obj = false;
            for (int u = 0; u < cnt; ++u) {
                float bx = s_gx[u], by = s_gy[u], bw = s_gw[u], bh = s_gh[u];
                float uw = fmaxf(px + pw * 0.5f, bx + bw * 0.5f) - fminf(px - pw * 0.5f, bx - bw * 0.5f);
                float uh = fmaxf(py + ph * 0.5f, by + bh * 0.5f) - fminf(py - ph * 0.5f, by - bh * 0.5f);
                float cw = pw + bw - uw, chh = ph + bh - uh;
                float iou = 0.0f;
                if (cw > 0.0f && chh > 0.0f) {
                    float car = cw * chh;
                    iou = car / (parea + bw * bh - car);
                }
                maxiou = fmaxf(maxiou, iou);
                if (s_cell[u] == cell) { obj = true; tconf = iou; }  // IoU symmetric => tconf
            }
            float d = conf - (obj ? tconf : 0.0f);
            float scale = obj ? 5.0f : (maxiou > SIL ? 0.0f : 1.0f);
            lsum += 0.5f * scale * d * d;
        }
    }

    // ---- block reduction -> per-block partial (no global atomics) ----
    for (int o = 32; o > 0; o >>= 1) lsum += __shfl_down(lsum, o, 64);
    if ((tid & 63) == 0) s_part[tid >> 6] = lsum;
    __syncthreads();
    if (tid == 0) {
        partials[blockIdx.y * P2_BLOCKS + blockIdx.x] =
            s_part[0] + s_part[1] + s_part[2] + s_part[3];
    }
}

__global__ __launch_bounds__(256) void final_reduce_kernel(
    const float* __restrict__ partials, float* __restrict__ loss)
{
    __shared__ float s_part[4];
    const int tid = threadIdx.x;
    float v = 0.0f;
    for (int i = tid; i < TOTAL_BLOCKS; i += 256) v += partials[i];
    for (int o = 32; o > 0; o >>= 1) v += __shfl_down(v, o, 64);
    if ((tid & 63) == 0) s_part[tid >> 6] = v;
    __syncthreads();
    if (tid == 0) loss[0] = (s_part[0] + s_part[1] + s_part[2] + s_part[3]) * (1.0f / NB);
}

extern "C" void kernel_launch(void* const* d_in, const int* in_sizes, int n_in,
                              void* d_out, int out_size, void* d_ws, size_t ws_size,
                              hipStream_t stream) {
    const float* out_p    = (const float*)d_in[0];
    const float* target_p = (const float*)d_in[1];
    const float* anchor_p = (const float*)d_in[2];
    float* loss_p    = (float*)d_out;
    float* partial_p = (float*)d_ws;   // TOTAL_BLOCKS floats

    dim3 grid(P2_BLOCKS, NB);
    yolo_loss_kernel<<<grid, dim3(256), 0, stream>>>(out_p, target_p, anchor_p, partial_p);
    final_reduce_kernel<<<dim3(1), dim3(256), 0, stream>>>(partial_p, loss_p);
}